// Round 1
// baseline (273.925 us; speedup 1.0000x reference)
//
#include <hip/hip_runtime.h>
#include <math.h>

// Problem constants
constexpr int Bn = 2048;   // batch
constexpr int Mn = 4;      // modalities
constexpr int Cn = 512;    // concepts
constexpr int Dn = 256;    // proj dim

constexpr size_t LOGITS_OFF = 0;
constexpr size_t R_OFF      = (size_t)Bn * Cn;              // 1048576
constexpr size_t SIM_OFF    = R_OFF + (size_t)Bn*Mn*Cn;     // 5242880
constexpr size_t CTR_OFF    = SIM_OFF + (size_t)Bn*Mn*Cn;   // 9437184

struct ProjArgs {
  const float* f[4];
  const float* W[4];
  const float* b[4];
  const float* g[4];
  const float* be[4];
  int K[4];
};

__device__ __forceinline__ void fma4(float4& a, float s, const float4& w) {
  a.x += s * w.x; a.y += s * w.y; a.z += s * w.z; a.w += s * w.w;
}

// K0: invU[c] = 1 / (||U[c]|| + 1e-6). One wave per concept row.
__global__ __launch_bounds__(256) void invu_kernel(const float* __restrict__ U,
                                                   float* __restrict__ invU) {
  int c = blockIdx.x * 4 + (threadIdx.x >> 6);   // 0..511
  int lane = threadIdx.x & 63;
  float4 v = *(const float4*)&U[(size_t)c * Dn + lane * 4];
  float s = v.x*v.x + v.y*v.y + v.z*v.z + v.w*v.w;
  #pragma unroll
  for (int m = 32; m >= 1; m >>= 1) s += __shfl_xor(s, m, 64);
  if (lane == 0) invU[c] = 1.0f / (sqrtf(s) + 1e-6f);
}

// K1: per modality, Y = f @ W^T + b, LayerNorm(g,be), write Z and invZ (l2 scale).
// Block: 32 rows x 256 cols (full D so LN stays in-block). 256 threads,
// thread tile 4 rows x 8 cols. K tiled by 32.
__global__ __launch_bounds__(256) void proj_ln_kernel(ProjArgs a,
                                                      float* __restrict__ Z,
                                                      float* __restrict__ invZ) {
  const int m = blockIdx.y;
  const int row0 = blockIdx.x * 32;
  const int K = a.K[m];
  const float* __restrict__ F  = a.f[m];
  const float* __restrict__ Wm = a.W[m];

  __shared__ float fs[32][36];      // [r][k], stride 36 keeps rows 16B-aligned
  __shared__ float wsm[32][260];    // [k][c] transposed W tile

  const int tid = threadIdx.x;
  const int cg = tid & 31;          // col group: cols cg*8 .. cg*8+7
  const int ty = tid >> 5;          // 0..7 ; rows ty + 8*i

  float4 acc[4][2];
  #pragma unroll
  for (int i = 0; i < 4; i++) { acc[i][0] = make_float4(0,0,0,0); acc[i][1] = make_float4(0,0,0,0); }

  const int fr = tid >> 3, fk = (tid & 7) * 4;   // f-tile load map
  const int wk = (tid & 7) * 4, wc = tid >> 3;   // W-tile load map

  for (int k0 = 0; k0 < K; k0 += 32) {
    // stage f tile: 32x32
    {
      float4 v = *(const float4*)&F[(size_t)(row0 + fr) * K + k0 + fk];
      fs[fr][fk+0] = v.x; fs[fr][fk+1] = v.y; fs[fr][fk+2] = v.z; fs[fr][fk+3] = v.w;
    }
    // stage W tile transposed: 256 cols x 32 k
    #pragma unroll
    for (int i = 0; i < 8; i++) {
      int c = wc + 32 * i;
      float4 v = *(const float4*)&Wm[(size_t)c * K + k0 + wk];
      wsm[wk+0][c] = v.x; wsm[wk+1][c] = v.y; wsm[wk+2][c] = v.z; wsm[wk+3][c] = v.w;
    }
    __syncthreads();
    #pragma unroll
    for (int k = 0; k < 32; k++) {
      float4 w0 = *(const float4*)&wsm[k][cg*8];
      float4 w1 = *(const float4*)&wsm[k][cg*8+4];
      #pragma unroll
      for (int i = 0; i < 4; i++) {
        float fv = fs[ty + 8*i][k];
        fma4(acc[i][0], fv, w0);
        fma4(acc[i][1], fv, w1);
      }
    }
    __syncthreads();
  }

  // epilogue: bias + LayerNorm + l2 stats
  float bb[8], gg[8], ee[8];
  {
    const float4* b4  = (const float4*)a.b[m];
    const float4* g4  = (const float4*)a.g[m];
    const float4* e4  = (const float4*)a.be[m];
    *(float4*)&bb[0] = b4[cg*2];  *(float4*)&bb[4] = b4[cg*2+1];
    *(float4*)&gg[0] = g4[cg*2];  *(float4*)&gg[4] = g4[cg*2+1];
    *(float4*)&ee[0] = e4[cg*2];  *(float4*)&ee[4] = e4[cg*2+1];
  }

  #pragma unroll
  for (int i = 0; i < 4; i++) {
    float* y = (float*)&acc[i][0];   // 8 contiguous floats
    float s = 0.f, s2 = 0.f;
    #pragma unroll
    for (int j = 0; j < 8; j++) { y[j] += bb[j]; s += y[j]; s2 += y[j]*y[j]; }
    // reduce across the 32 threads (same ty) that own this row
    #pragma unroll
    for (int msk = 16; msk >= 1; msk >>= 1) {
      s  += __shfl_xor(s,  msk, 64);
      s2 += __shfl_xor(s2, msk, 64);
    }
    float mu  = s * (1.0f/256.0f);
    float var = s2 * (1.0f/256.0f) - mu*mu;
    float rs  = rsqrtf(var + 1e-5f);
    float z[8]; float zs = 0.f;
    #pragma unroll
    for (int j = 0; j < 8; j++) { z[j] = (y[j] - mu) * rs * gg[j] + ee[j]; zs += z[j]*z[j]; }
    #pragma unroll
    for (int msk = 16; msk >= 1; msk >>= 1) zs += __shfl_xor(zs, msk, 64);
    float inv = 1.0f / (sqrtf(zs) + 1e-6f);
    int bm = (row0 + ty + 8*i) * Mn + m;
    float* zp = Z + (size_t)bm * Dn + cg*8;
    *(float4*)zp       = *(float4*)&z[0];
    *(float4*)(zp + 4) = *(float4*)&z[4];
    if (cg == 0) invZ[bm] = inv;
  }
}

// K2: dual GEMM. A = Z [8192 x 256]; B1 = U, B2 = O [512 x 256].
// sim = (Z.U) * invZ * invU / tau -> d_out[SIM]; ojzi = Z.O raw -> d_out[CTR].
// Block tile 64 rows x 128 cols, K tiled by 32. Thread tile 4r x 8c x 2 mats.
__global__ __launch_bounds__(256) void dual_gemm_kernel(
    const float* __restrict__ Z, const float* __restrict__ U, const float* __restrict__ O,
    const float* __restrict__ invZ, const float* __restrict__ invU,
    float* __restrict__ out) {
  const int row0 = blockIdx.x * 64;     // bm rows
  const int col0 = blockIdx.y * 128;    // concept cols

  __shared__ float as_[64][36];
  __shared__ float us_[32][132];
  __shared__ float os_[32][132];

  const int tid = threadIdx.x;
  const int tx = tid & 15;     // cols tx*8
  const int ty = tid >> 4;     // rows ty + 16*i

  float4 aU[4][2], aO[4][2];
  #pragma unroll
  for (int i = 0; i < 4; i++) {
    aU[i][0] = make_float4(0,0,0,0); aU[i][1] = make_float4(0,0,0,0);
    aO[i][0] = make_float4(0,0,0,0); aO[i][1] = make_float4(0,0,0,0);
  }

  const int ar = tid >> 2, ak = (tid & 3) * 8;
  const int uc = tid >> 1, uk = (tid & 1) * 16;

  for (int k0 = 0; k0 < Dn; k0 += 32) {
    {
      const float* src = Z + (size_t)(row0 + ar) * Dn + k0 + ak;
      float4 v0 = *(const float4*)src;
      float4 v1 = *(const float4*)(src + 4);
      float* d = &as_[ar][ak];
      d[0]=v0.x; d[1]=v0.y; d[2]=v0.z; d[3]=v0.w;
      d[4]=v1.x; d[5]=v1.y; d[6]=v1.z; d[7]=v1.w;
    }
    {
      const float* su = U + (size_t)(col0 + uc) * Dn + k0 + uk;
      const float* so = O + (size_t)(col0 + uc) * Dn + k0 + uk;
      #pragma unroll
      for (int i = 0; i < 4; i++) {
        float4 v = *(const float4*)(su + 4*i);
        us_[uk+4*i+0][uc] = v.x; us_[uk+4*i+1][uc] = v.y;
        us_[uk+4*i+2][uc] = v.z; us_[uk+4*i+3][uc] = v.w;
        float4 w = *(const float4*)(so + 4*i);
        os_[uk+4*i+0][uc] = w.x; os_[uk+4*i+1][uc] = w.y;
        os_[uk+4*i+2][uc] = w.z; os_[uk+4*i+3][uc] = w.w;
      }
    }
    __syncthreads();
    #pragma unroll
    for (int k = 0; k < 32; k++) {
      float4 u0 = *(const float4*)&us_[k][tx*8];
      float4 u1 = *(const float4*)&us_[k][tx*8+4];
      float4 o0 = *(const float4*)&os_[k][tx*8];
      float4 o1 = *(const float4*)&os_[k][tx*8+4];
      #pragma unroll
      for (int i = 0; i < 4; i++) {
        float av = as_[ty + 16*i][k];
        fma4(aU[i][0], av, u0); fma4(aU[i][1], av, u1);
        fma4(aO[i][0], av, o0); fma4(aO[i][1], av, o1);
      }
    }
    __syncthreads();
  }

  const float inv_tau = 1.0f / 0.07f;
  float iu[8];
  *(float4*)&iu[0] = *(const float4*)&invU[col0 + tx*8];
  *(float4*)&iu[4] = *(const float4*)&invU[col0 + tx*8 + 4];

  #pragma unroll
  for (int i = 0; i < 4; i++) {
    int bm = row0 + ty + 16*i;
    float iz = invZ[bm] * inv_tau;
    float* su = (float*)&aU[i][0];
    float* so = (float*)&aO[i][0];
    float simv[8];
    #pragma unroll
    for (int j = 0; j < 8; j++) simv[j] = su[j] * iz * iu[j];
    size_t base = (size_t)bm * Cn + col0 + tx*8;
    *(float4*)&out[SIM_OFF + base]     = *(float4*)&simv[0];
    *(float4*)&out[SIM_OFF + base + 4] = *(float4*)&simv[4];
    *(float4*)&out[CTR_OFF + base]     = *(float4*)&so[0];
    *(float4*)&out[CTR_OFF + base + 4] = *(float4*)&so[4];
  }
}

// K3: softmax over modalities, contrib = ojzi * r (in place), logits = sum + bias.
__global__ __launch_bounds__(256) void finalize_kernel(float* __restrict__ out,
                                                       const float* __restrict__ cls_bias) {
  int gid = blockIdx.x * 256 + threadIdx.x;   // 0 .. B*C-1
  int b = gid >> 9, c = gid & 511;
  size_t base = (size_t)b * Mn * Cn + c;
  float s0 = out[SIM_OFF + base];
  float s1 = out[SIM_OFF + base + 512];
  float s2 = out[SIM_OFF + base + 1024];
  float s3 = out[SIM_OFF + base + 1536];
  float mx = fmaxf(fmaxf(s0, s1), fmaxf(s2, s3));
  float e0 = expf(s0 - mx), e1 = expf(s1 - mx), e2 = expf(s2 - mx), e3 = expf(s3 - mx);
  float inv = 1.0f / (e0 + e1 + e2 + e3);
  float r0 = e0*inv, r1 = e1*inv, r2 = e2*inv, r3 = e3*inv;
  float o0 = out[CTR_OFF + base];
  float o1 = out[CTR_OFF + base + 512];
  float o2 = out[CTR_OFF + base + 1024];
  float o3 = out[CTR_OFF + base + 1536];
  float c0 = o0*r0, c1 = o1*r1, c2 = o2*r2, c3 = o3*r3;
  out[R_OFF + base]          = r0;
  out[R_OFF + base + 512]    = r1;
  out[R_OFF + base + 1024]   = r2;
  out[R_OFF + base + 1536]   = r3;
  out[CTR_OFF + base]        = c0;
  out[CTR_OFF + base + 512]  = c1;
  out[CTR_OFF + base + 1024] = c2;
  out[CTR_OFF + base + 1536] = c3;
  out[LOGITS_OFF + (size_t)b * Cn + c] = c0 + c1 + c2 + c3 + cls_bias[c];
}

extern "C" void kernel_launch(void* const* d_in, const int* in_sizes, int n_in,
                              void* d_out, int out_size, void* d_ws, size_t ws_size,
                              hipStream_t stream) {
  ProjArgs pa;
  const int fi[4]  = {0, 5, 10, 15};
  const int Ks[4]  = {1024, 1024, 512, 256};
  for (int m = 0; m < 4; m++) {
    pa.f[m]  = (const float*)d_in[fi[m] + 0];
    pa.W[m]  = (const float*)d_in[fi[m] + 1];
    pa.b[m]  = (const float*)d_in[fi[m] + 2];
    pa.g[m]  = (const float*)d_in[fi[m] + 3];
    pa.be[m] = (const float*)d_in[fi[m] + 4];
    pa.K[m]  = Ks[m];
  }
  const float* U        = (const float*)d_in[20];
  const float* O        = (const float*)d_in[21];
  const float* cls_bias = (const float*)d_in[22];

  float* ws   = (float*)d_ws;
  float* Z    = ws;                        // 2048*4*256 = 2,097,152 floats
  float* invZ = ws + 2097152;              // 8192 floats
  float* invU = invZ + 8192;               // 512 floats

  float* out = (float*)d_out;

  invu_kernel<<<128, 256, 0, stream>>>(U, invU);
  proj_ln_kernel<<<dim3(Bn/32, 4), 256, 0, stream>>>(pa, Z, invZ);
  dual_gemm_kernel<<<dim3((Bn*Mn)/64, Cn/128), 256, 0, stream>>>(Z, U, O, invZ, invU, out);
  finalize_kernel<<<(Bn*Cn)/256, 256, 0, stream>>>(out, cls_bias);
}

// Round 2
// 192.693 us; speedup vs baseline: 1.4216x; 1.4216x over previous
//
#include <hip/hip_runtime.h>
#include <math.h>

typedef __attribute__((ext_vector_type(8))) short short8;
typedef __attribute__((ext_vector_type(4))) float f32x4;

constexpr int Bn = 2048, Mn = 4, Cn = 512, Dn = 256;
constexpr size_t LOGITS_OFF = 0;
constexpr size_t R_OFF   = (size_t)Bn * Cn;                 // 1,048,576
constexpr size_t SIM_OFF = R_OFF + (size_t)Bn * Mn * Cn;    // 5,242,880
constexpr size_t CTR_OFF = SIM_OFF + (size_t)Bn * Mn * Cn;  // 9,437,184
constexpr float INV_TAU = 1.0f / 0.07f;

__device__ __forceinline__ unsigned short f2bf(float f) {
  unsigned u = __float_as_uint(f);
  u += 0x7fffu + ((u >> 16) & 1u);   // round-to-nearest-even
  return (unsigned short)(u >> 16);
}

__device__ __forceinline__ void gload16(const void* g, void* l) {
  __builtin_amdgcn_global_load_lds(
      (const __attribute__((address_space(1))) void*)g,
      (__attribute__((address_space(3))) void*)l, 16, 0, 0);
}

// ---------------- K0a: fp32 -> bf16 conversions (W x4, U, O) ----------------
struct CvtArgs {
  const float* src[6];
  unsigned short* dst[6];
  int n[6];
};

__global__ __launch_bounds__(256) void cvt_kernel(CvtArgs a) {
  int arr = blockIdx.y;
  int idx = (blockIdx.x * 256 + threadIdx.x) * 8;
  if (idx >= a.n[arr]) return;
  const float4* s = (const float4*)(a.src[arr] + idx);
  float4 v0 = s[0], v1 = s[1];
  uint4 p;
  p.x = f2bf(v0.x) | ((unsigned)f2bf(v0.y) << 16);
  p.y = f2bf(v0.z) | ((unsigned)f2bf(v0.w) << 16);
  p.z = f2bf(v1.x) | ((unsigned)f2bf(v1.y) << 16);
  p.w = f2bf(v1.z) | ((unsigned)f2bf(v1.w) << 16);
  *(uint4*)(a.dst[arr] + idx) = p;
}

// ---------------- K0b: invU[c] = 1/(||U[c]||+1e-6) ----------------
__global__ __launch_bounds__(256) void invu_kernel(const float* __restrict__ U,
                                                   float* __restrict__ invU) {
  int c = blockIdx.x * 4 + (threadIdx.x >> 6);
  int lane = threadIdx.x & 63;
  float4 v = *(const float4*)&U[(size_t)c * Dn + lane * 4];
  float s = v.x*v.x + v.y*v.y + v.z*v.z + v.w*v.w;
  #pragma unroll
  for (int m = 32; m >= 1; m >>= 1) s += __shfl_xor(s, m, 64);
  if (lane == 0) invU[c] = 1.0f / (sqrtf(s) + 1e-6f);
}

// ---------------- K1: proj + LN + l2 stats, bf16 MFMA ----------------
// Block: 32 rows x 256 cols (full D), 128 threads = 2 waves, each wave owns
// 16 rows x 256 cols (1 M-frag x 16 N-frags of 16x16x32). LN fully in-wave.
// LDS is 16B-chunk-major [kchunk][row|col] -> conflict-free ds_read_b128.
struct ProjArgs {
  const float* f[4];
  const float* b[4];
  const float* g[4];
  const float* be[4];
  const unsigned short* Wb[4];
  int K[4];
};

__global__ __launch_bounds__(128) void proj_kernel(ProjArgs a,
                                                   unsigned short* __restrict__ Zb,
                                                   float* __restrict__ invZ) {
  const int m = blockIdx.y;
  const int row0 = blockIdx.x * 32;
  const int K = a.K[m];
  const float* __restrict__ F = a.f[m];
  const unsigned short* __restrict__ Wm = a.Wb[m];

  __shared__ unsigned short aS[4 * 32 * 8];    // 2 KB  [kc][row] chunks
  __shared__ unsigned short bS[4 * 256 * 8];   // 16 KB [kc][col] chunks
  __shared__ unsigned short zS[32][264];       // transpose buffer for Z store

  const int tid = threadIdx.x;
  const int w = tid >> 6;
  const int l = tid & 63;
  const int rg = l >> 4, c16 = l & 15;

  f32x4 acc[16];
  #pragma unroll
  for (int i = 0; i < 16; i++) acc[i] = (f32x4){0.f, 0.f, 0.f, 0.f};

  const int abase = ((l >> 4) * 32 + w * 16 + c16) * 8;   // ushort index
  const int bbase = ((l >> 4) * 256 + c16) * 8;

  const int akc = tid >> 5;        // 0..3
  const int arow = tid & 31;       // 0..31
  const float* fsrc = F + (size_t)(row0 + arow) * K + akc * 8;

  for (int k0 = 0; k0 < K; k0 += 32) {
    // stage B tile (256 cols x 32 k, bf16) via global_load_lds: 16 issues
    #pragma unroll
    for (int ii = 0; ii < 8; ii++) {
      int i = w + 2 * ii;
      int kc = i >> 2, col = (i & 3) * 64 + l;
      gload16(Wm + (size_t)col * K + k0 + kc * 8, &bS[i * 512]);
    }
    // stage A tile (32 rows x 32 k) fp32 -> bf16
    {
      const float4* s = (const float4*)(fsrc + k0);
      float4 v0 = s[0], v1 = s[1];
      uint4 p;
      p.x = f2bf(v0.x) | ((unsigned)f2bf(v0.y) << 16);
      p.y = f2bf(v0.z) | ((unsigned)f2bf(v0.w) << 16);
      p.z = f2bf(v1.x) | ((unsigned)f2bf(v1.y) << 16);
      p.w = f2bf(v1.z) | ((unsigned)f2bf(v1.w) << 16);
      *(uint4*)&aS[tid * 8] = p;
    }
    __syncthreads();
    short8 av = *(const short8*)&aS[abase];
    #pragma unroll
    for (int nf = 0; nf < 16; nf++) {
      short8 bv = *(const short8*)&bS[bbase + nf * 128];
      acc[nf] = __builtin_amdgcn_mfma_f32_16x16x32_bf16(av, bv, acc[nf], 0, 0, 0);
    }
    __syncthreads();
  }

  // ---- epilogue: bias + LayerNorm + l2 stats, all in-wave ----
  float bb[16], gg[16], ee[16];
  #pragma unroll
  for (int nf = 0; nf < 16; nf++) {
    bb[nf] = a.b[m][nf * 16 + c16];
    gg[nf] = a.g[m][nf * 16 + c16];
    ee[nf] = a.be[m][nf * 16 + c16];
  }
  float s[4] = {0, 0, 0, 0}, s2[4] = {0, 0, 0, 0};
  #pragma unroll
  for (int nf = 0; nf < 16; nf++) {
    #pragma unroll
    for (int j = 0; j < 4; j++) {
      float y = acc[nf][j] + bb[nf];
      acc[nf][j] = y;
      s[j] += y; s2[j] += y * y;
    }
  }
  #pragma unroll
  for (int msk = 8; msk >= 1; msk >>= 1) {
    #pragma unroll
    for (int j = 0; j < 4; j++) {
      s[j]  += __shfl_xor(s[j],  msk, 64);
      s2[j] += __shfl_xor(s2[j], msk, 64);
    }
  }
  float mu[4], rs[4];
  #pragma unroll
  for (int j = 0; j < 4; j++) {
    mu[j] = s[j] * (1.0f / 256.0f);
    float var = s2[j] * (1.0f / 256.0f) - mu[j] * mu[j];
    rs[j] = rsqrtf(var + 1e-5f);
  }
  float zs[4] = {0, 0, 0, 0};
  #pragma unroll
  for (int nf = 0; nf < 16; nf++) {
    #pragma unroll
    for (int j = 0; j < 4; j++) {
      float z = (acc[nf][j] - mu[j]) * rs[j] * gg[nf] + ee[nf];
      acc[nf][j] = z;
      zs[j] += z * z;
    }
  }
  #pragma unroll
  for (int msk = 8; msk >= 1; msk >>= 1) {
    #pragma unroll
    for (int j = 0; j < 4; j++) zs[j] += __shfl_xor(zs[j], msk, 64);
  }
  float inv[4];
  #pragma unroll
  for (int j = 0; j < 4; j++) inv[j] = 1.0f / (sqrtf(zs[j]) + 1e-6f);

  if (c16 < 4) {
    float v = (c16 == 0) ? inv[0] : (c16 == 1) ? inv[1] : (c16 == 2) ? inv[2] : inv[3];
    int local = w * 16 + rg * 4 + c16;
    invZ[(size_t)(row0 + local) * 4 + m] = v;
  }
  // write z (bf16) to transpose buffer, then vectorized dump to Zb
  #pragma unroll
  for (int nf = 0; nf < 16; nf++) {
    #pragma unroll
    for (int j = 0; j < 4; j++)
      zS[w * 16 + rg * 4 + j][nf * 16 + c16] = f2bf(acc[nf][j]);
  }
  __syncthreads();
  #pragma unroll
  for (int i = 0; i < 8; i++) {
    int c = tid + i * 128;               // 0..1023 chunks of 8
    int row = c >> 5, colc = (c & 31) * 8;
    uint4 v = *(const uint4*)&zS[row][colc];
    *(uint4*)(Zb + ((size_t)(row0 + row) * 4 + m) * 256 + colc) = v;
  }
}

// ---------------- K2: dual GEMM + softmax/finalize fused ----------------
// A = Zb [8192 x 256] bf16; B1 = Ub, B2 = Ob [512 x 256] bf16.
// Block 64 rows x 128 cols, 256 threads = 4 waves (2x2), BK=32, K=256.
// C/D frag: col = lane&15, row = (lane>>4)*4 + j  ->  j == modality.
__global__ __launch_bounds__(256) void dual_kernel(
    const unsigned short* __restrict__ Zb,
    const unsigned short* __restrict__ Ub,
    const unsigned short* __restrict__ Ob,
    const float* __restrict__ invZ, const float* __restrict__ invU,
    const float* __restrict__ cls_bias, float* __restrict__ out) {
  const int row0 = blockIdx.x * 64;
  const int col0 = blockIdx.y * 128;

  __shared__ unsigned short aS[4 * 64 * 8];    // 4 KB
  __shared__ unsigned short uS[4 * 128 * 8];   // 8 KB
  __shared__ unsigned short oS[4 * 128 * 8];   // 8 KB

  const int tid = threadIdx.x;
  const int w = tid >> 6, l = tid & 63;
  const int wm = w >> 1, wc = w & 1;
  const int rg = l >> 4, c16 = l & 15;

  f32x4 accU[2][4], accO[2][4];
  #pragma unroll
  for (int i = 0; i < 2; i++)
    #pragma unroll
    for (int j = 0; j < 4; j++) {
      accU[i][j] = (f32x4){0.f, 0.f, 0.f, 0.f};
      accO[i][j] = (f32x4){0.f, 0.f, 0.f, 0.f};
    }

  const int abase = ((l >> 4) * 64 + wm * 32 + c16) * 8;   // + mf*128
  const int ubase = ((l >> 4) * 128 + wc * 64 + c16) * 8;  // + nf*128

  for (int k0 = 0; k0 < 256; k0 += 32) {
    #pragma unroll
    for (int ii = 0; ii < 5; ii++) {
      int i = w + 4 * ii;   // wave-uniform
      if (i < 4) {
        gload16(Zb + (size_t)(row0 + l) * 256 + k0 + i * 8, &aS[i * 512]);
      } else if (i < 12) {
        int j = i - 4;
        int kc = j >> 1, col = (j & 1) * 64 + l;
        gload16(Ub + (size_t)(col0 + col) * 256 + k0 + kc * 8, &uS[j * 512]);
      } else {
        int j = i - 12;
        int kc = j >> 1, col = (j & 1) * 64 + l;
        gload16(Ob + (size_t)(col0 + col) * 256 + k0 + kc * 8, &oS[j * 512]);
      }
    }
    __syncthreads();
    short8 av0 = *(const short8*)&aS[abase];
    short8 av1 = *(const short8*)&aS[abase + 128];
    #pragma unroll
    for (int nf = 0; nf < 4; nf++) {
      short8 uv = *(const short8*)&uS[ubase + nf * 128];
      accU[0][nf] = __builtin_amdgcn_mfma_f32_16x16x32_bf16(av0, uv, accU[0][nf], 0, 0, 0);
      accU[1][nf] = __builtin_amdgcn_mfma_f32_16x16x32_bf16(av1, uv, accU[1][nf], 0, 0, 0);
      short8 ov = *(const short8*)&oS[ubase + nf * 128];
      accO[0][nf] = __builtin_amdgcn_mfma_f32_16x16x32_bf16(av0, ov, accO[0][nf], 0, 0, 0);
      accO[1][nf] = __builtin_amdgcn_mfma_f32_16x16x32_bf16(av1, ov, accO[1][nf], 0, 0, 0);
    }
    __syncthreads();
  }

  // ---- fused epilogue: sim, softmax over modalities (register-local), r,
  //      contrib, logits ----
  #pragma unroll
  for (int mf = 0; mf < 2; mf++) {
    int bmb = row0 + wm * 32 + mf * 16 + rg * 4;     // multiple of 4
    f32x4 iz = *(const f32x4*)&invZ[bmb];
    int bidx = bmb >> 2;
    #pragma unroll
    for (int nf = 0; nf < 4; nf++) {
      int col = col0 + wc * 64 + nf * 16 + c16;
      float iu = invU[col] * INV_TAU;
      f32x4 sU = accU[mf][nf], sO = accO[mf][nf];
      float sim0 = sU[0] * iz[0] * iu;
      float sim1 = sU[1] * iz[1] * iu;
      float sim2 = sU[2] * iz[2] * iu;
      float sim3 = sU[3] * iz[3] * iu;
      float mx = fmaxf(fmaxf(sim0, sim1), fmaxf(sim2, sim3));
      float e0 = __expf(sim0 - mx), e1 = __expf(sim1 - mx);
      float e2 = __expf(sim2 - mx), e3 = __expf(sim3 - mx);
      float rinv = 1.0f / (e0 + e1 + e2 + e3);
      float r0 = e0 * rinv, r1 = e1 * rinv, r2 = e2 * rinv, r3 = e3 * rinv;
      float ct0 = sO[0] * r0, ct1 = sO[1] * r1, ct2 = sO[2] * r2, ct3 = sO[3] * r3;
      size_t sb = (size_t)bmb * Cn + col;
      out[SIM_OFF + sb]          = sim0;
      out[SIM_OFF + sb + Cn]     = sim1;
      out[SIM_OFF + sb + 2*Cn]   = sim2;
      out[SIM_OFF + sb + 3*Cn]   = sim3;
      out[R_OFF + sb]            = r0;
      out[R_OFF + sb + Cn]       = r1;
      out[R_OFF + sb + 2*Cn]     = r2;
      out[R_OFF + sb + 3*Cn]     = r3;
      out[CTR_OFF + sb]          = ct0;
      out[CTR_OFF + sb + Cn]     = ct1;
      out[CTR_OFF + sb + 2*Cn]   = ct2;
      out[CTR_OFF + sb + 3*Cn]   = ct3;
      out[LOGITS_OFF + (size_t)bidx * Cn + col] =
          ct0 + ct1 + ct2 + ct3 + cls_bias[col];
    }
  }
}

extern "C" void kernel_launch(void* const* d_in, const int* in_sizes, int n_in,
                              void* d_out, int out_size, void* d_ws, size_t ws_size,
                              hipStream_t stream) {
  const int fi[4] = {0, 5, 10, 15};
  const int Ks[4] = {1024, 1024, 512, 256};

  // workspace layout (bytes)
  char* ws = (char*)d_ws;
  unsigned short* Zb  = (unsigned short*)(ws + 0);           // 4,194,304 B
  unsigned short* Wb0 = (unsigned short*)(ws + 4194304);     // 524,288
  unsigned short* Wb1 = (unsigned short*)(ws + 4718592);     // 524,288
  unsigned short* Wb2 = (unsigned short*)(ws + 5242880);     // 262,144
  unsigned short* Wb3 = (unsigned short*)(ws + 5505024);     // 131,072
  unsigned short* Ub  = (unsigned short*)(ws + 5636096);     // 262,144
  unsigned short* Ob  = (unsigned short*)(ws + 5898240);     // 262,144
  float* invZ         = (float*)(ws + 6160384);              // 32,768
  float* invU         = (float*)(ws + 6193152);              // 2,048
  unsigned short* Wb[4] = {Wb0, Wb1, Wb2, Wb3};

  ProjArgs pa;
  for (int m = 0; m < 4; m++) {
    pa.f[m]  = (const float*)d_in[fi[m] + 0];
    pa.b[m]  = (const float*)d_in[fi[m] + 2];
    pa.g[m]  = (const float*)d_in[fi[m] + 3];
    pa.be[m] = (const float*)d_in[fi[m] + 4];
    pa.Wb[m] = Wb[m];
    pa.K[m]  = Ks[m];
  }
  const float* U        = (const float*)d_in[20];
  const float* O        = (const float*)d_in[21];
  const float* cls_bias = (const float*)d_in[22];

  CvtArgs ca;
  ca.src[0] = (const float*)d_in[1];   ca.dst[0] = Wb0; ca.n[0] = 262144;
  ca.src[1] = (const float*)d_in[6];   ca.dst[1] = Wb1; ca.n[1] = 262144;
  ca.src[2] = (const float*)d_in[11];  ca.dst[2] = Wb2; ca.n[2] = 131072;
  ca.src[3] = (const float*)d_in[16];  ca.dst[3] = Wb3; ca.n[3] = 65536;
  ca.src[4] = U;                       ca.dst[4] = Ub;  ca.n[4] = 131072;
  ca.src[5] = O;                       ca.dst[5] = Ob;  ca.n[5] = 131072;

  float* out = (float*)d_out;

  cvt_kernel<<<dim3(128, 6), 256, 0, stream>>>(ca);
  invu_kernel<<<128, 256, 0, stream>>>(U, invU);
  proj_kernel<<<dim3(Bn / 32, 4), 128, 0, stream>>>(pa, Zb, invZ);
  dual_kernel<<<dim3((Bn * Mn) / 64, Cn / 128), 256, 0, stream>>>(
      Zb, Ub, Ob, invZ, invU, cls_bias, out);
}